// Round 7
// baseline (1351.640 us; speedup 1.0000x reference)
//
#include <hip/hip_runtime.h>
#include <hip/hip_bf16.h>

typedef __attribute__((ext_vector_type(8))) __bf16 bf16x8;
typedef __attribute__((ext_vector_type(4))) float f32x4;
typedef __attribute__((ext_vector_type(8))) float f32x8;

static __device__ __forceinline__ unsigned short bf16r(float f) {
  unsigned u = __builtin_bit_cast(unsigned, f);
  return (unsigned short)((u + 0x7FFFu + ((u >> 16) & 1u)) >> 16);
}

// tanh(x) = 1 - 2/(exp2(x*2*log2e)+1); saturates correctly for |x| large.
static __device__ __forceinline__ float ftanh(float x) {
  float e = __builtin_amdgcn_exp2f(x * 2.8853900817779268f);
  return 1.0f - 2.0f * __builtin_amdgcn_rcpf(e + 1.0f);
}

// global->LDS direct copy, 16B per lane (dest = wave-uniform base + lane*16)
static __device__ __forceinline__ void gload_lds16(const void* g, void* l) {
  __builtin_amdgcn_global_load_lds(
      (const __attribute__((address_space(1))) unsigned int*)g,
      (__attribute__((address_space(3))) unsigned int*)l, 16, 0, 0);
}

// ---------------- prologue: pack weights (bf16, frag order) + params --------
// ws layout (bytes):
//   w1pk: [0, 131072)          8 mtiles x 16 ksteps x 64 lanes x 8 bf16 (IDENTITY k)
//   w2pk: [131072, 163840)     8 mtiles x 4 ksteps x 64 lanes x 8 bf16 (pi-permuted k)
//   w3pk: [163840, 196608)     same as w2pk
//   ppk : [196608, 200192)     7 params x [q=4][32] f32
// w1 identity k-order: reg-loaded obs gives lane (q,rl) floats [q*8, q*8+8)
// of each 32-float kstep -> k-slot (q,j) <-> col s*32 + q*8 + j.
__global__ void pack_kernel(const float* __restrict__ w1, const float* __restrict__ w2,
                            const float* __restrict__ w3, const float* __restrict__ b1,
                            const float* __restrict__ g1, const float* __restrict__ be1,
                            const float* __restrict__ b2, const float* __restrict__ g2,
                            const float* __restrict__ be2, const float* __restrict__ b3,
                            unsigned short* __restrict__ w1pk, unsigned short* __restrict__ w2pk,
                            unsigned short* __restrict__ w3pk, float* __restrict__ ppk) {
  int idx = blockIdx.x * 256 + threadIdx.x;
  if (idx < 65536) {            // w1, identity k-order
    int j = idx & 7, l = (idx >> 3) & 63, s = (idx >> 9) & 15, t = idx >> 13;
    int row = t * 16 + (l & 15);
    int col = s * 32 + (l >> 4) * 8 + j;
    w1pk[idx] = bf16r(w1[row * 512 + col]);
  } else if (idx < 81920) {     // w2, pi-permuted k-order
    int i = idx - 65536;
    int j = i & 7, l = (i >> 3) & 63, s = (i >> 9) & 3, t = i >> 11;
    int row = t * 16 + (l & 15);
    int col = (2 * s + (j >> 2)) * 16 + (l >> 4) * 4 + (j & 3);
    w2pk[i] = bf16r(w2[row * 128 + col]);
  } else if (idx < 98304) {     // w3, pi-permuted k-order
    int i = idx - 81920;
    int j = i & 7, l = (i >> 3) & 63, s = (i >> 9) & 3, t = i >> 11;
    int row = t * 16 + (l & 15);
    int col = (2 * s + (j >> 2)) * 16 + (l >> 4) * 4 + (j & 3);
    w3pk[i] = bf16r(w3[row * 128 + col]);
  } else if (idx < 99200) {     // params: b1,g1,be1,b2,g2,be2,b3
    int i = idx - 98304;        // 0..895
    int p = i >> 7;
    int r = i & 127;
    int qq = r >> 5, ii = r & 31;
    int m = (ii >> 2) * 16 + qq * 4 + (ii & 3);
    const float* src = (p == 0) ? b1 : (p == 1) ? g1 : (p == 2) ? be1
                     : (p == 3) ? b2 : (p == 4) ? g2 : (p == 5) ? be2 : b3;
    ppk[i] = src[m];
  }
}

// ---------------- fused backbone: persistent 4-chunk, baseline body ---------
// R18. R17 (-47%) showed w1 frags MUST be LDS-fed (L1 path = ~150 GB/s/CU,
// 8MB/CU of frag traffic = the regression). R15 spilled. So: attack the
// read-silent tail (GEMM2/3 L2 frags ~7.4us + epilogue VALU ~3us + w1
// refill/barrier ~2.5us per round = ~13us x 4 rounds of HBM-dead time =
// the 188-vs-135 gap) with MINIMAL deltas to the proven 188us codegen:
//  (1) grid 256 x 1024thr, 4 chunks/block: w1 fill ONCE (saves 3 fills +
//      barriers), chunk boundaries barrier-free (waves free-run).
//  (2) issue slots bb=6,7 (idle in baseline) prefetch next chunk's batches
//      0,1 into the SAME st[2][4] -> 128 KB/CU of next-chunk reads in
//      flight through each tail. Zero new registers.
//  (3) w2pk in the free 32KB of LDS (filled once with w1): GEMM2's frag
//      reads leave L2 -> tail shrinks + chip-wide L2 pressure halves.
// Predicted 150-168us. ~185 = wave drift already covers this -> read-phase
// BW is the residual suspect. Regression = reg-fit broke (check top-5).
__global__ __launch_bounds__(1024)
__attribute__((amdgpu_waves_per_eu(4, 4)))
void backbone_main(const float* __restrict__ obs,
                   const unsigned char* __restrict__ w1pk_g,
                   const unsigned char* __restrict__ w2pk_g,
                   const bf16x8* __restrict__ w3pk,
                   const float* __restrict__ ppk,
                   float* __restrict__ out) {
  __shared__ __align__(16) unsigned char lds[163840];   // w1:128K | w2:32K

  const int tid  = threadIdx.x;
  const int lane = tid & 63;
  const int wv   = tid >> 6;          // 0..15
  const int q    = lane >> 4;
  const int rl   = lane & 15;
  // block owns 256 rows per chunk; chunk stride = 256 blocks * 256 rows.
  const size_t row0 = (size_t)blockIdx.x * 256 + (unsigned)(wv * 16) + (unsigned)rl;
  const size_t CROWS = (size_t)256 * 256;   // 65536 rows per chunk step

  f32x4 st[2][4];
#define LOAD_BATCH(buf, P, s0)                                                   \
  do {                                                                           \
    st[buf][0] = __builtin_nontemporal_load((const f32x4*)((P) + (s0) * 32));    \
    st[buf][1] = __builtin_nontemporal_load((const f32x4*)((P) + (s0) * 32 + 4));\
    st[buf][2] = __builtin_nontemporal_load((const f32x4*)((P) + (s0) * 32 + 32));\
    st[buf][3] = __builtin_nontemporal_load((const f32x4*)((P) + (s0) * 32 + 36));\
  } while (0)

  // preload chunk-0 batches 0,1 (hide under LDS fill latency)
  {
    const float* p00 = obs + row0 * 512 + q * 8;
    LOAD_BATCH(0, p00, 0);
    LOAD_BATCH(1, p00, 2);
  }

  // fill w1 (128KB, 8 rounds) + w2 (32KB, 2 rounds) into LDS -- once.
#pragma unroll
  for (int r = 0; r < 8; ++r) {
    gload_lds16(w1pk_g + r * 16384 + tid * 16, lds + r * 16384 + wv * 1024);
  }
#pragma unroll
  for (int r = 0; r < 2; ++r) {
    gload_lds16(w2pk_g + r * 16384 + tid * 16, lds + 131072 + r * 16384 + wv * 1024);
  }
  __syncthreads();   // the only barrier in the kernel

  const bf16x8* w1l = (const bf16x8*)lds;             // frag (t,s): [(t*16+s)*64+lane]
  const bf16x8* w2l = (const bf16x8*)(lds + 131072);  // frag (t,s): [(t*4+s)*64+lane]

#pragma unroll 1
  for (int c = 0; c < 4; ++c) {
    const size_t brow = row0 + (size_t)c * CROWS;
    const float* pc  = obs + brow * 512 + q * 8;      // this chunk
    const float* pcn = pc + CROWS * 512;              // next chunk

    f32x4 acc[8];
#pragma unroll
    for (int t = 0; t < 8; ++t) acc[t] = (f32x4){0.f, 0.f, 0.f, 0.f};

    // ---- GEMM1: K=512, 8 batches x 2 ksteps, 2 in flight;
    //      bb=6,7 issue slots prefetch next chunk's batches 0,1 ----
#pragma unroll
    for (int bb = 0; bb < 8; ++bb) {
      const int cur = bb & 1;
      f32x4 a0 = st[cur][0], a1 = st[cur][1];
      f32x4 a2 = st[cur][2], a3 = st[cur][3];
      if (bb < 6) {
        LOAD_BATCH(cur, pc, 2 * bb + 4);
      } else if (c < 3) {
        LOAD_BATCH(cur, pcn, 2 * (bb - 6));
      }
      f32x8 r0 = {a0.x, a0.y, a0.z, a0.w, a1.x, a1.y, a1.z, a1.w};
      f32x8 r1 = {a2.x, a2.y, a2.z, a2.w, a3.x, a3.y, a3.z, a3.w};
      bf16x8 b0 = __builtin_convertvector(r0, bf16x8);
      bf16x8 b1 = __builtin_convertvector(r1, bf16x8);
#pragma unroll
      for (int t = 0; t < 8; ++t) {
        bf16x8 af0 = w1l[(t * 16 + 2 * bb) * 64 + lane];
        acc[t] = __builtin_amdgcn_mfma_f32_16x16x32_bf16(af0, b0, acc[t], 0, 0, 0);
      }
#pragma unroll
      for (int t = 0; t < 8; ++t) {
        bf16x8 af1 = w1l[(t * 16 + 2 * bb + 1) * 64 + lane];
        acc[t] = __builtin_amdgcn_mfma_f32_16x16x32_bf16(af1, b1, acc[t], 0, 0, 0);
      }
    }

    bf16x8 pkv[4];

    // ---- epilogue 1: +b1, LayerNorm(g1,be1), tanh, pack bf16 ----
    {
      const float* pb = ppk + 0 * 128 + q * 32;
      const float* pg = ppk + 1 * 128 + q * 32;
      const float* pe = ppk + 2 * 128 + q * 32;
      float s1 = 0.f, s2 = 0.f;
#pragma unroll
      for (int t = 0; t < 8; ++t) {
        f32x4 bb = *(const f32x4*)(pb + t * 4);
        f32x4 v = acc[t];
        v.x += bb.x; v.y += bb.y; v.z += bb.z; v.w += bb.w;
        acc[t] = v;
        s1 += (v.x + v.y) + (v.z + v.w);
        s2 += (v.x * v.x + v.y * v.y) + (v.z * v.z + v.w * v.w);
      }
      s1 += __shfl_xor(s1, 16, 64);
      s1 += __shfl_xor(s1, 32, 64);
      s2 += __shfl_xor(s2, 16, 64);
      s2 += __shfl_xor(s2, 32, 64);
      float mu  = s1 * (1.0f / 128.0f);
      float var = s2 * (1.0f / 128.0f) - mu * mu;
      float rs  = __builtin_amdgcn_rsqf(var + 1e-5f);
#pragma unroll
      for (int t2 = 0; t2 < 4; ++t2) {
        f32x4 ga = *(const f32x4*)(pg + (2 * t2) * 4);
        f32x4 gb = *(const f32x4*)(pg + (2 * t2 + 1) * 4);
        f32x4 ea = *(const f32x4*)(pe + (2 * t2) * 4);
        f32x4 eb = *(const f32x4*)(pe + (2 * t2 + 1) * 4);
        f32x4 va = acc[2 * t2];
        f32x4 vb = acc[2 * t2 + 1];
        f32x8 cat = {ftanh((va.x - mu) * rs * ga.x + ea.x),
                     ftanh((va.y - mu) * rs * ga.y + ea.y),
                     ftanh((va.z - mu) * rs * ga.z + ea.z),
                     ftanh((va.w - mu) * rs * ga.w + ea.w),
                     ftanh((vb.x - mu) * rs * gb.x + eb.x),
                     ftanh((vb.y - mu) * rs * gb.y + eb.y),
                     ftanh((vb.z - mu) * rs * gb.z + eb.z),
                     ftanh((vb.w - mu) * rs * gb.w + eb.w)};
        pkv[t2] = __builtin_convertvector(cat, bf16x8);
      }
    }

    // ---- GEMM2: K=128 (4 ksteps), w2 frags from LDS ----
#pragma unroll
    for (int t = 0; t < 8; ++t) acc[t] = (f32x4){0.f, 0.f, 0.f, 0.f};
#pragma unroll
    for (int s = 0; s < 4; ++s) {
#pragma unroll
      for (int t = 0; t < 8; ++t) {
        bf16x8 af = w2l[(t * 4 + s) * 64 + lane];
        acc[t] = __builtin_amdgcn_mfma_f32_16x16x32_bf16(af, pkv[s], acc[t], 0, 0, 0);
      }
    }

    // ---- epilogue 2: +b2, LayerNorm(g2,be2), tanh, pack ----
    {
      const float* pb = ppk + 3 * 128 + q * 32;
      const float* pg = ppk + 4 * 128 + q * 32;
      const float* pe = ppk + 5 * 128 + q * 32;
      float s1 = 0.f, s2 = 0.f;
#pragma unroll
      for (int t = 0; t < 8; ++t) {
        f32x4 bb = *(const f32x4*)(pb + t * 4);
        f32x4 v = acc[t];
        v.x += bb.x; v.y += bb.y; v.z += bb.z; v.w += bb.w;
        acc[t] = v;
        s1 += (v.x + v.y) + (v.z + v.w);
        s2 += (v.x * v.x + v.y * v.y) + (v.z * v.z + v.w * v.w);
      }
      s1 += __shfl_xor(s1, 16, 64);
      s1 += __shfl_xor(s1, 32, 64);
      s2 += __shfl_xor(s2, 16, 64);
      s2 += __shfl_xor(s2, 32, 64);
      float mu  = s1 * (1.0f / 128.0f);
      float var = s2 * (1.0f / 128.0f) - mu * mu;
      float rs  = __builtin_amdgcn_rsqf(var + 1e-5f);
#pragma unroll
      for (int t2 = 0; t2 < 4; ++t2) {
        f32x4 ga = *(const f32x4*)(pg + (2 * t2) * 4);
        f32x4 gb = *(const f32x4*)(pg + (2 * t2 + 1) * 4);
        f32x4 ea = *(const f32x4*)(pe + (2 * t2) * 4);
        f32x4 eb = *(const f32x4*)(pe + (2 * t2 + 1) * 4);
        f32x4 va = acc[2 * t2];
        f32x4 vb = acc[2 * t2 + 1];
        f32x8 cat = {ftanh((va.x - mu) * rs * ga.x + ea.x),
                     ftanh((va.y - mu) * rs * ga.y + ea.y),
                     ftanh((va.z - mu) * rs * ga.z + ea.z),
                     ftanh((va.w - mu) * rs * ga.w + ea.w),
                     ftanh((vb.x - mu) * rs * gb.x + eb.x),
                     ftanh((vb.y - mu) * rs * gb.y + eb.y),
                     ftanh((vb.z - mu) * rs * gb.z + eb.z),
                     ftanh((vb.w - mu) * rs * gb.w + eb.w)};
        pkv[t2] = __builtin_convertvector(cat, bf16x8);
      }
    }

    // ---- GEMM3: w3 frags from global (L2-cached) ----
#pragma unroll
    for (int t = 0; t < 8; ++t) acc[t] = (f32x4){0.f, 0.f, 0.f, 0.f};
#pragma unroll
    for (int s = 0; s < 4; ++s) {
#pragma unroll
      for (int t = 0; t < 8; ++t) {
        bf16x8 af = w3pk[(t * 4 + s) * 64 + lane];
        acc[t] = __builtin_amdgcn_mfma_f32_16x16x32_bf16(af, pkv[s], acc[t], 0, 0, 0);
      }
    }

    // ---- final: +b3, tanh, store fp32 (dwordx4, nontemporal) ----
    {
      const float* pb = ppk + 6 * 128 + q * 32;
      float* orow = out + brow * 128 + q * 4;
#pragma unroll
      for (int t = 0; t < 8; ++t) {
        f32x4 bb = *(const f32x4*)(pb + t * 4);
        f32x4 v = acc[t];
        f32x4 o = {ftanh(v.x + bb.x), ftanh(v.y + bb.y),
                   ftanh(v.z + bb.z), ftanh(v.w + bb.w)};
        __builtin_nontemporal_store(o, (f32x4*)(orow + t * 16));
      }
    }
  }
#undef LOAD_BATCH
}

extern "C" void kernel_launch(void* const* d_in, const int* in_sizes, int n_in,
                              void* d_out, int out_size, void* d_ws, size_t ws_size,
                              hipStream_t stream) {
  const float* obs = (const float*)d_in[0];
  const float* w1  = (const float*)d_in[1];
  const float* b1  = (const float*)d_in[2];
  const float* g1  = (const float*)d_in[3];
  const float* be1 = (const float*)d_in[4];
  const float* w2  = (const float*)d_in[5];
  const float* b2  = (const float*)d_in[6];
  const float* g2  = (const float*)d_in[7];
  const float* be2 = (const float*)d_in[8];
  const float* w3  = (const float*)d_in[9];
  const float* b3  = (const float*)d_in[10];

  unsigned short* w1pk = (unsigned short*)d_ws;
  unsigned short* w2pk = w1pk + 65536;
  unsigned short* w3pk = w2pk + 16384;
  float*          ppk  = (float*)(w3pk + 16384);

  pack_kernel<<<388, 256, 0, stream>>>(w1, w2, w3, b1, g1, be1, b2, g2, be2, b3,
                                       w1pk, w2pk, w3pk, ppk);

  // persistent-style: 256 blocks x 1024 thr; each block = 4 chunks x 256 rows
  backbone_main<<<256, 1024, 0, stream>>>(obs, (const unsigned char*)w1pk,
                                          (const unsigned char*)w2pk,
                                          (const bf16x8*)w3pk,
                                          ppk, (float*)d_out);
}

// Round 8
// 272.588 us; speedup vs baseline: 4.9585x; 4.9585x over previous
//
#include <hip/hip_runtime.h>
#include <hip/hip_bf16.h>

typedef __attribute__((ext_vector_type(8))) __bf16 bf16x8;
typedef __attribute__((ext_vector_type(4))) float f32x4;
typedef __attribute__((ext_vector_type(8))) float f32x8;

static __device__ __forceinline__ unsigned short bf16r(float f) {
  unsigned u = __builtin_bit_cast(unsigned, f);
  return (unsigned short)((u + 0x7FFFu + ((u >> 16) & 1u)) >> 16);
}

// tanh(x) = 1 - 2/(exp2(x*2*log2e)+1); saturates correctly for |x| large.
static __device__ __forceinline__ float ftanh(float x) {
  float e = __builtin_amdgcn_exp2f(x * 2.8853900817779268f);
  return 1.0f - 2.0f * __builtin_amdgcn_rcpf(e + 1.0f);
}

// global->LDS direct copy, 16B per lane (dest = wave-uniform base + lane*16)
static __device__ __forceinline__ void gload_lds16(const void* g, void* l) {
  __builtin_amdgcn_global_load_lds(
      (const __attribute__((address_space(1))) unsigned int*)g,
      (__attribute__((address_space(3))) unsigned int*)l, 16, 0, 0);
}

// ---------------- prologue: pack weights (bf16, frag order) + params --------
// ws layout (bytes):
//   w1pk: [0, 131072)          8 mtiles x 16 ksteps x 64 lanes x 8 bf16 (IDENTITY k)
//   w2pk: [131072, 163840)     8 mtiles x 4 ksteps x 64 lanes x 8 bf16 (pi-permuted k)
//   w3pk: [163840, 196608)     same as w2pk
//   ppk : [196608, 200192)     7 params x [q=4][32] f32
// w1 identity k-order: reg-loaded obs gives lane (q,rl) floats [q*8, q*8+8)
// of each 32-float kstep -> k-slot (q,j) <-> col s*32 + q*8 + j.
__global__ void pack_kernel(const float* __restrict__ w1, const float* __restrict__ w2,
                            const float* __restrict__ w3, const float* __restrict__ b1,
                            const float* __restrict__ g1, const float* __restrict__ be1,
                            const float* __restrict__ b2, const float* __restrict__ g2,
                            const float* __restrict__ be2, const float* __restrict__ b3,
                            unsigned short* __restrict__ w1pk, unsigned short* __restrict__ w2pk,
                            unsigned short* __restrict__ w3pk, float* __restrict__ ppk) {
  int idx = blockIdx.x * 256 + threadIdx.x;
  if (idx < 65536) {            // w1, identity k-order
    int j = idx & 7, l = (idx >> 3) & 63, s = (idx >> 9) & 15, t = idx >> 13;
    int row = t * 16 + (l & 15);
    int col = s * 32 + (l >> 4) * 8 + j;
    w1pk[idx] = bf16r(w1[row * 512 + col]);
  } else if (idx < 81920) {     // w2, pi-permuted k-order
    int i = idx - 65536;
    int j = i & 7, l = (i >> 3) & 63, s = (i >> 9) & 3, t = i >> 11;
    int row = t * 16 + (l & 15);
    int col = (2 * s + (j >> 2)) * 16 + (l >> 4) * 4 + (j & 3);
    w2pk[i] = bf16r(w2[row * 128 + col]);
  } else if (idx < 98304) {     // w3, pi-permuted k-order
    int i = idx - 81920;
    int j = i & 7, l = (i >> 3) & 63, s = (i >> 9) & 3, t = i >> 11;
    int row = t * 16 + (l & 15);
    int col = (2 * s + (j >> 2)) * 16 + (l >> 4) * 4 + (j & 3);
    w3pk[i] = bf16r(w3[row * 128 + col]);
  } else if (idx < 99200) {     // params: b1,g1,be1,b2,g2,be2,b3
    int i = idx - 98304;        // 0..895
    int p = i >> 7;
    int r = i & 127;
    int qq = r >> 5, ii = r & 31;
    int m = (ii >> 2) * 16 + qq * 4 + (ii & 3);
    const float* src = (p == 0) ? b1 : (p == 1) ? g1 : (p == 2) ? be1
                     : (p == 3) ? b2 : (p == 4) ? g2 : (p == 5) ? be2 : b3;
    ppk[i] = src[m];
  }
}

// ---------------- fused backbone: 2 blocks/CU via half-LDS w1 ---------------
// R19. R15/R18 post-mortem: ANY persistent chunk loop wrapping this body
// breaks regalloc (R15: spill at 128; R18: allocator chose 64 VGPR, 1.2GB
// scratch traffic each way). R17: pure-L1 w1 frags = -47% (8MB/CU @ ~150
// GB/s). Surviving model: ~10-13us read-silent tail per round x 4 rounds,
// unfixable at 1 block/CU (128KB LDS). Fix WITHOUT a loop:
//  - 512-thr blocks (8 waves, 128 rows), 2048 blocks; body byte-identical.
//  - w1 ksteps 0..7 in LDS (64KB, batches bb<4); ksteps 8..15 read from
//    global (bb>=4) -- 64KB stream shared by all 16 resident waves: first
//    touch L2, then L1 hits; ~1MB/CU/round hides under the 21us HBM phase
//    (8x less than R17's failure mode).
//  - LDS 64KB/block -> 2 blocks/CU, 16 waves = 4/SIMD at the proven 128-reg
//    budget. Block A's tail overlaps block B's reads; pairs de-phase.
// Predicted 155-175us. Spill -> backbone in top-5 with WRITE blowup.
// Null ~188 -> tail-overlap dead end; next = two-kernel split or roofline.
__global__ __launch_bounds__(512)
__attribute__((amdgpu_waves_per_eu(4, 4)))
void backbone_main(const float* __restrict__ obs,
                   const unsigned char* __restrict__ w1pk_g,
                   const bf16x8* __restrict__ w2pk,
                   const bf16x8* __restrict__ w3pk,
                   const float* __restrict__ ppk,
                   float* __restrict__ out) {
  __shared__ __align__(16) unsigned char w1s[65536];   // ksteps 0..7 only

  const int tid  = threadIdx.x;
  const int lane = tid & 63;
  const int wv   = tid >> 6;          // 0..7
  const int q    = lane >> 4;
  const int rl   = lane & 15;
  // block owns 128 consecutive rows; wave owns 16 of them.
  const size_t brow = (size_t)blockIdx.x * 128 + (unsigned)(wv * 16) + (unsigned)rl;

  // lane q owns floats [q*8, q*8+8) of each 32-float kstep (identity map).
  const float* p0 = obs + brow * 512 + q * 8;

  f32x4 st[2][4];
#define LOAD_BATCH(buf, s0)                                                      \
  do {                                                                           \
    st[buf][0] = __builtin_nontemporal_load((const f32x4*)(p0 + (s0) * 32));     \
    st[buf][1] = __builtin_nontemporal_load((const f32x4*)(p0 + (s0) * 32 + 4)); \
    st[buf][2] = __builtin_nontemporal_load((const f32x4*)(p0 + (s0) * 32 + 32));\
    st[buf][3] = __builtin_nontemporal_load((const f32x4*)(p0 + (s0) * 32 + 36));\
  } while (0)

  // preload batches 0,1 (hide under LDS fill latency)
  LOAD_BATCH(0, 0);
  LOAD_BATCH(1, 2);

  // fill w1 ksteps 0..7 into LDS: per mtile t, first 8KB of its 16KB.
  // 8 rounds x (512 threads x 16B) = 64KB.
#pragma unroll
  for (int r = 0; r < 8; ++r) {
    gload_lds16(w1pk_g + r * 16384 + tid * 16, w1s + r * 8192 + wv * 1024);
  }
  __syncthreads();   // the only barrier in the kernel

  const bf16x8* w1l = (const bf16x8*)w1s;       // frag (t, s<8): [(t*8+s)*64 + lane]
  const bf16x8* w1g = (const bf16x8*)w1pk_g;    // frag (t, s):   [(t*16+s)*64 + lane]

  f32x4 acc[8];
#pragma unroll
  for (int t = 0; t < 8; ++t) acc[t] = (f32x4){0.f, 0.f, 0.f, 0.f};

  // ---- GEMM1: K=512, 8 batches x 2 ksteps, 2 batches in flight.
  //      bb<4: frags from LDS (ksteps 0..7); bb>=4: frags from global
  //      (ksteps 8..15; L1/L2-shared stream across all resident waves) ----
#pragma unroll
  for (int bb = 0; bb < 8; ++bb) {
    const int cur = bb & 1;
    f32x4 a0 = st[cur][0], a1 = st[cur][1];
    f32x4 a2 = st[cur][2], a3 = st[cur][3];
    if (bb < 6) {
      LOAD_BATCH(cur, 2 * bb + 4);
    }
    f32x8 r0 = {a0.x, a0.y, a0.z, a0.w, a1.x, a1.y, a1.z, a1.w};
    f32x8 r1 = {a2.x, a2.y, a2.z, a2.w, a3.x, a3.y, a3.z, a3.w};
    bf16x8 b0 = __builtin_convertvector(r0, bf16x8);
    bf16x8 b1 = __builtin_convertvector(r1, bf16x8);
    if (bb < 4) {
#pragma unroll
      for (int t = 0; t < 8; ++t) {
        bf16x8 af0 = w1l[(t * 8 + 2 * bb) * 64 + lane];
        acc[t] = __builtin_amdgcn_mfma_f32_16x16x32_bf16(af0, b0, acc[t], 0, 0, 0);
      }
#pragma unroll
      for (int t = 0; t < 8; ++t) {
        bf16x8 af1 = w1l[(t * 8 + 2 * bb + 1) * 64 + lane];
        acc[t] = __builtin_amdgcn_mfma_f32_16x16x32_bf16(af1, b1, acc[t], 0, 0, 0);
      }
    } else {
#pragma unroll
      for (int t = 0; t < 8; ++t) {
        bf16x8 af0 = w1g[(t * 16 + 2 * bb) * 64 + lane];
        acc[t] = __builtin_amdgcn_mfma_f32_16x16x32_bf16(af0, b0, acc[t], 0, 0, 0);
      }
#pragma unroll
      for (int t = 0; t < 8; ++t) {
        bf16x8 af1 = w1g[(t * 16 + 2 * bb + 1) * 64 + lane];
        acc[t] = __builtin_amdgcn_mfma_f32_16x16x32_bf16(af1, b1, acc[t], 0, 0, 0);
      }
    }
  }
#undef LOAD_BATCH

  bf16x8 pkv[4];

  // ---- epilogue 1: +b1, LayerNorm(g1,be1), tanh, pack bf16 ----
  {
    const float* pb = ppk + 0 * 128 + q * 32;
    const float* pg = ppk + 1 * 128 + q * 32;
    const float* pe = ppk + 2 * 128 + q * 32;
    float s1 = 0.f, s2 = 0.f;
#pragma unroll
    for (int t = 0; t < 8; ++t) {
      f32x4 bb = *(const f32x4*)(pb + t * 4);
      f32x4 v = acc[t];
      v.x += bb.x; v.y += bb.y; v.z += bb.z; v.w += bb.w;
      acc[t] = v;
      s1 += (v.x + v.y) + (v.z + v.w);
      s2 += (v.x * v.x + v.y * v.y) + (v.z * v.z + v.w * v.w);
    }
    s1 += __shfl_xor(s1, 16, 64);
    s1 += __shfl_xor(s1, 32, 64);
    s2 += __shfl_xor(s2, 16, 64);
    s2 += __shfl_xor(s2, 32, 64);
    float mu  = s1 * (1.0f / 128.0f);
    float var = s2 * (1.0f / 128.0f) - mu * mu;
    float rs  = __builtin_amdgcn_rsqf(var + 1e-5f);
#pragma unroll
    for (int t2 = 0; t2 < 4; ++t2) {
      f32x4 ga = *(const f32x4*)(pg + (2 * t2) * 4);
      f32x4 gb = *(const f32x4*)(pg + (2 * t2 + 1) * 4);
      f32x4 ea = *(const f32x4*)(pe + (2 * t2) * 4);
      f32x4 eb = *(const f32x4*)(pe + (2 * t2 + 1) * 4);
      f32x4 va = acc[2 * t2];
      f32x4 vb = acc[2 * t2 + 1];
      f32x8 cat = {ftanh((va.x - mu) * rs * ga.x + ea.x),
                   ftanh((va.y - mu) * rs * ga.y + ea.y),
                   ftanh((va.z - mu) * rs * ga.z + ea.z),
                   ftanh((va.w - mu) * rs * ga.w + ea.w),
                   ftanh((vb.x - mu) * rs * gb.x + eb.x),
                   ftanh((vb.y - mu) * rs * gb.y + eb.y),
                   ftanh((vb.z - mu) * rs * gb.z + eb.z),
                   ftanh((vb.w - mu) * rs * gb.w + eb.w)};
      pkv[t2] = __builtin_convertvector(cat, bf16x8);
    }
  }

  // ---- GEMM2: K=128 (4 ksteps), B-frags are the lane's own pkv regs ----
#pragma unroll
  for (int t = 0; t < 8; ++t) acc[t] = (f32x4){0.f, 0.f, 0.f, 0.f};
#pragma unroll
  for (int s = 0; s < 4; ++s) {
#pragma unroll
    for (int t = 0; t < 8; ++t) {
      bf16x8 af = w2pk[(t * 4 + s) * 64 + lane];
      acc[t] = __builtin_amdgcn_mfma_f32_16x16x32_bf16(af, pkv[s], acc[t], 0, 0, 0);
    }
  }

  // ---- epilogue 2: +b2, LayerNorm(g2,be2), tanh, pack ----
  {
    const float* pb = ppk + 3 * 128 + q * 32;
    const float* pg = ppk + 4 * 128 + q * 32;
    const float* pe = ppk + 5 * 128 + q * 32;
    float s1 = 0.f, s2 = 0.f;
#pragma unroll
    for (int t = 0; t < 8; ++t) {
      f32x4 bb = *(const f32x4*)(pb + t * 4);
      f32x4 v = acc[t];
      v.x += bb.x; v.y += bb.y; v.z += bb.z; v.w += bb.w;
      acc[t] = v;
      s1 += (v.x + v.y) + (v.z + v.w);
      s2 += (v.x * v.x + v.y * v.y) + (v.z * v.z + v.w * v.w);
    }
    s1 += __shfl_xor(s1, 16, 64);
    s1 += __shfl_xor(s1, 32, 64);
    s2 += __shfl_xor(s2, 16, 64);
    s2 += __shfl_xor(s2, 32, 64);
    float mu  = s1 * (1.0f / 128.0f);
    float var = s2 * (1.0f / 128.0f) - mu * mu;
    float rs  = __builtin_amdgcn_rsqf(var + 1e-5f);
#pragma unroll
    for (int t2 = 0; t2 < 4; ++t2) {
      f32x4 ga = *(const f32x4*)(pg + (2 * t2) * 4);
      f32x4 gb = *(const f32x4*)(pg + (2 * t2 + 1) * 4);
      f32x4 ea = *(const f32x4*)(pe + (2 * t2) * 4);
      f32x4 eb = *(const f32x4*)(pe + (2 * t2 + 1) * 4);
      f32x4 va = acc[2 * t2];
      f32x4 vb = acc[2 * t2 + 1];
      f32x8 cat = {ftanh((va.x - mu) * rs * ga.x + ea.x),
                   ftanh((va.y - mu) * rs * ga.y + ea.y),
                   ftanh((va.z - mu) * rs * ga.z + ea.z),
                   ftanh((va.w - mu) * rs * ga.w + ea.w),
                   ftanh((vb.x - mu) * rs * gb.x + eb.x),
                   ftanh((vb.y - mu) * rs * gb.y + eb.y),
                   ftanh((vb.z - mu) * rs * gb.z + eb.z),
                   ftanh((vb.w - mu) * rs * gb.w + eb.w)};
      pkv[t2] = __builtin_convertvector(cat, bf16x8);
    }
  }

  // ---- GEMM3 ----
#pragma unroll
  for (int t = 0; t < 8; ++t) acc[t] = (f32x4){0.f, 0.f, 0.f, 0.f};
#pragma unroll
  for (int s = 0; s < 4; ++s) {
#pragma unroll
    for (int t = 0; t < 8; ++t) {
      bf16x8 af = w3pk[(t * 4 + s) * 64 + lane];
      acc[t] = __builtin_amdgcn_mfma_f32_16x16x32_bf16(af, pkv[s], acc[t], 0, 0, 0);
    }
  }

  // ---- final: +b3, tanh, store fp32 (dwordx4, nontemporal) ----
  {
    const float* pb = ppk + 6 * 128 + q * 32;
    float* orow = out + brow * 128 + q * 4;
#pragma unroll
    for (int t = 0; t < 8; ++t) {
      f32x4 bb = *(const f32x4*)(pb + t * 4);
      f32x4 v = acc[t];
      f32x4 o = {ftanh(v.x + bb.x), ftanh(v.y + bb.y),
                 ftanh(v.z + bb.z), ftanh(v.w + bb.w)};
      __builtin_nontemporal_store(o, (f32x4*)(orow + t * 16));
    }
  }
}

extern "C" void kernel_launch(void* const* d_in, const int* in_sizes, int n_in,
                              void* d_out, int out_size, void* d_ws, size_t ws_size,
                              hipStream_t stream) {
  const float* obs = (const float*)d_in[0];
  const float* w1  = (const float*)d_in[1];
  const float* b1  = (const float*)d_in[2];
  const float* g1  = (const float*)d_in[3];
  const float* be1 = (const float*)d_in[4];
  const float* w2  = (const float*)d_in[5];
  const float* b2  = (const float*)d_in[6];
  const float* g2  = (const float*)d_in[7];
  const float* be2 = (const float*)d_in[8];
  const float* w3  = (const float*)d_in[9];
  const float* b3  = (const float*)d_in[10];

  unsigned short* w1pk = (unsigned short*)d_ws;
  unsigned short* w2pk = w1pk + 65536;
  unsigned short* w3pk = w2pk + 16384;
  float*          ppk  = (float*)(w3pk + 16384);

  pack_kernel<<<388, 256, 0, stream>>>(w1, w2, w3, b1, g1, be1, b2, g2, be2, b3,
                                       w1pk, w2pk, w3pk, ppk);

  // 2048 blocks x 512 thr; each block = 128 rows; 64KB LDS -> 2 blocks/CU
  backbone_main<<<2048, 512, 0, stream>>>(obs, (const unsigned char*)w1pk,
                                          (const bf16x8*)w2pk, (const bf16x8*)w3pk,
                                          ppk, (float*)d_out);
}